// Round 17
// baseline (480.045 us; speedup 1.0000x reference)
//
#include <hip/hip_runtime.h>
#include <cstdint>

#define NN 100000
#define NE 1600000
#define DI 9
#define DD 128
#define NH 8
#define NG 1000
#define LOG2E 1.44269504f

#define NBK 196             // buckets = dst>>9 (512 nodes each; 196*512 >= 100000)
#define NBLK 256            // partition blocks
#define EPB (NE/NBLK)       // 6250 edges per block (exact)

typedef unsigned int uint;
typedef __attribute__((ext_vector_type(8))) short bf16x8;
typedef __attribute__((ext_vector_type(4))) float f32x4;

__device__ __forceinline__ float leaky(float x){ return fmaxf(x, 0.2f*x); }
__device__ __forceinline__ uint f2bf(float f){            // round-to-nearest-even bf16
  uint u = __float_as_uint(f);
  return (u + 0x7fffu + ((u>>16)&1u)) >> 16;
}
__device__ __forceinline__ float bflo(uint p){ return __uint_as_float(p << 16); }
__device__ __forceinline__ float bfhi(uint p){ return __uint_as_float(p & 0xffff0000u); }
__device__ __forceinline__ uint packbf(float a, float b){ return f2bf(a) | (f2bf(b)<<16); }
__device__ __forceinline__ float rdlanef(float v, int l){
  return __uint_as_float((uint)__builtin_amdgcn_readlane((int)__float_as_uint(v), l));
}

union U16 { uint4 u; bf16x8 v; };
__device__ __forceinline__ bf16x8 ld8(const uint* p){ U16 t; t.u = *(const uint4*)p; return t.v; }

// ================= CSR build: atomic-free bucket partition (512-node buckets) =================
// ebuf packing: src (20 bits) | dst_low9 << 20
__global__ __launch_bounds__(512) void k_hist(const int* __restrict__ dst, int* __restrict__ hist){
  __shared__ int h[NBK];
  for (int i = threadIdx.x; i < NBK; i += 512) h[i] = 0;
  __syncthreads();
  int blk = blockIdx.x;
  int beg = blk*EPB, end = beg + EPB;
  for (int i = beg + threadIdx.x; i < end; i += 512)
    atomicAdd(&h[dst[i] >> 9], 1);
  __syncthreads();
  for (int b = threadIdx.x; b < NBK; b += 512) hist[blk*NBK + b] = h[b];
}

// merged bsum + bscan: one block
__global__ __launch_bounds__(256) void k_bsumscan(int* __restrict__ hist, int* __restrict__ bsum,
                                                  int* __restrict__ bbase){
  __shared__ int sh[256];
  int t = threadIdx.x;
  int run = 0;
  if (t < NBK){
    for (int k = 0; k < NBLK; ++k){
      int v = hist[k*NBK + t];
      hist[k*NBK + t] = run;
      run += v;
    }
    bsum[t] = run;
  }
  sh[t] = (t < NBK) ? run : 0;
  __syncthreads();
  for (int off = 1; off < 256; off <<= 1){
    int v = (t >= off) ? sh[t-off] : 0;
    __syncthreads();
    sh[t] += v;
    __syncthreads();
  }
  if (t < NBK) bbase[t] = sh[t] - run;
}

__global__ __launch_bounds__(512) void k_part(const int* __restrict__ src, const int* __restrict__ dst,
    const int* __restrict__ hist, const int* __restrict__ bbase, uint* __restrict__ ebuf){
  __shared__ int cur[NBK];
  int blk = blockIdx.x;
  for (int b = threadIdx.x; b < NBK; b += 512)
    cur[b] = hist[blk*NBK + b] + bbase[b];
  __syncthreads();
  int beg = blk*EPB, end = beg + EPB;
  for (int i = beg + threadIdx.x; i < end; i += 512){
    int d = dst[i], s = src[i];
    int b = d >> 9;
    int p = atomicAdd(&cur[b], 1);              // LDS atomic; runs of ~32 edges (128B) per cursor
    ebuf[p] = (uint)s | ((uint)(d & 511) << 20);
  }
}

// per 512-node bucket: count-sort by dst_low9; writes rowptr AND col
__global__ __launch_bounds__(256) void k_fin(const uint* __restrict__ ebuf, const int* __restrict__ bbase,
    const int* __restrict__ bsum, int* __restrict__ rowptr, int* __restrict__ col){
  __shared__ int cnt[512];
  __shared__ int sc[256];
  int b = blockIdx.x;
  int t = threadIdx.x;
  int nb0 = b*512;
  int nodes = NN - nb0; if (nodes > 512) nodes = 512;
  cnt[t] = 0; cnt[t+256] = 0;
  __syncthreads();
  int base = bbase[b], n = bsum[b];
  for (int i = t; i < n; i += 256)
    atomicAdd(&cnt[ebuf[base+i] >> 20], 1);
  __syncthreads();
  int a0 = cnt[2*t], a1 = cnt[2*t+1];
  int pairsum = a0 + a1;
  sc[t] = pairsum;
  __syncthreads();
  for (int off = 1; off < 256; off <<= 1){
    int v = (t >= off) ? sc[t-off] : 0;
    __syncthreads();
    sc[t] += v;
    __syncthreads();
  }
  int excl = sc[t] - pairsum;        // exclusive over pairs
  __syncthreads();
  cnt[2*t]   = excl;
  cnt[2*t+1] = excl + a0;
  if (2*t   < nodes) rowptr[nb0 + 2*t]   = base + excl;
  if (2*t+1 < nodes) rowptr[nb0 + 2*t+1] = base + excl + a0;
  __syncthreads();
  for (int i = t; i < n; i += 256){
    uint e = ebuf[base+i];
    int d = (int)(e >> 20);
    int r = atomicAdd(&cnt[d], 1);
    col[base + r] = (int)(e & 0xFFFFFu);
  }
  if (b == 0 && t == 0) rowptr[NN] = NE;
}

// ---------------- 5 weight converts in one launch ----------------
__global__ __launch_bounds__(64) void k_wconv5(const float* __restrict__ w0, const float* __restrict__ w1,
    const float* __restrict__ w2, const float* __restrict__ w3, const float* __restrict__ w4,
    uint* __restrict__ o0, uint* __restrict__ o1, uint* __restrict__ o2,
    uint* __restrict__ o3, uint* __restrict__ o4){
  int which = blockIdx.x >> 7;
  int n = blockIdx.x & 127;
  int t = threadIdx.x;
  const float* W = (which==0)?w0:(which==1)?w1:(which==2)?w2:(which==3)?w3:w4;
  uint* WT = (which==0)?o0:(which==1)?o1:(which==2)?o2:(which==3)?o3:o4;
  float a = W[(2*t)*DD + n];
  float b = W[(2*t+1)*DD + n];
  WT[n*64 + t] = packbf(a, b);
}

// ---------------- GAT1 linear (x@W1) + logits (pre-scaled by log2e); bf16 table ----------------
__global__ __launch_bounds__(128) void k_lin1(const float* __restrict__ x, const float* __restrict__ W1,
    const float* __restrict__ as1, const float* __restrict__ ad1,
    uint* __restrict__ t1b, float* __restrict__ al_s, float* __restrict__ al_d){
  int n = blockIdx.x;
  int c = threadIdx.x;
  const float* xr = x + n*DI;
  float t = 0.f;
  #pragma unroll
  for (int k = 0; k < DI; ++k) t = fmaf(xr[k], W1[k*DD+c], t);
  uint mybf = f2bf(t);
  uint pbf  = (uint)__shfl_xor((int)mybf, 1, 64);
  if (!(c & 1)) t1b[(size_t)n*64 + (c>>1)] = mybf | (pbf<<16);
  float vs = t * as1[c];
  float vd = t * ad1[c];
  #pragma unroll
  for (int m = 8; m >= 1; m >>= 1){ vs += __shfl_xor(vs, m, 16); vd += __shfl_xor(vd, m, 16); }
  if ((c & 15) == 0){
    al_s[n*NH + (c>>4)] = vs*LOG2E;
    al_d[n*NH + (c>>4)] = vd*LOG2E;
  }
}

// ---------------- GAT1 fused: scalar-uniform node, masked 16-edge chunks ----------------
__global__ __launch_bounds__(256) void k_gat1(const uint* __restrict__ t1b,
    const float* __restrict__ al_s, const float* __restrict__ al_d,
    const int* __restrict__ rowptr, const int* __restrict__ col,
    const float* __restrict__ b1, uint* __restrict__ outb){
  int n = __builtin_amdgcn_readfirstlane(blockIdx.x*4 + (int)(threadIdx.x >> 6));
  if (n >= NN) return;
  uint lane = threadIdx.x & 63;
  uint h = lane >> 3;
  float ald = al_d[(uint)n*NH + h];
  float a0  = exp2f(leaky(al_s[(uint)n*NH + h] + ald));   // self-loop
  uint  ps  = t1b[(uint)n*64u + lane];
  float den = a0;
  float s0 = a0*bflo(ps), s1 = a0*bfhi(ps);
  int beg = rowptr[n], end = rowptr[n+1];
  for (int e = beg; e < end; e += 16){
    int cs[16]; float ls[16]; uint pp[16];
    #pragma unroll
    for (int j = 0; j < 16; ++j) cs[j] = __builtin_amdgcn_readfirstlane(col[e + j]);  // scalar (padded col)
    #pragma unroll
    for (int j = 0; j < 16; ++j){
      ls[j] = al_s[(uint)cs[j]*8u + h];          // SGPR base + small voffset
      pp[j] = t1b[(uint)cs[j]*64u + lane];       // SGPR base + lane voffset
    }
    #pragma unroll
    for (int j = 0; j < 16; ++j){
      float a = (e + j < end) ? exp2f(leaky(ls[j] + ald)) : 0.f;
      den += a;
      s0 = fmaf(a, bflo(pp[j]), s0);
      s1 = fmaf(a, bfhi(pp[j]), s1);
    }
  }
  float inv = 1.f/(den + 1e-16f);
  float2 bb = ((const float2*)b1)[lane];
  outb[(uint)n*64u + lane] = packbf(fmaxf(s0*inv + bb.x, 0.f), fmaxf(s1*inv + bb.y, 0.f));
}

// ---------------- GAT2 fused: scalar-uniform node, 64-edge chunks, readlane broadcast ----------------
__global__ __launch_bounds__(256) void k_gat2(const uint* __restrict__ t2b,
    const float* __restrict__ al_s, const float* __restrict__ al_d,
    const int* __restrict__ rowptr, const int* __restrict__ col,
    const float* __restrict__ b2, uint* __restrict__ outb){
  int n = __builtin_amdgcn_readfirstlane(blockIdx.x*4 + (int)(threadIdx.x >> 6));
  if (n >= NN) return;
  uint lane = threadIdx.x & 63;
  float ald = al_d[n];
  float a0  = exp2f(leaky(al_s[n] + ald));
  uint  ps  = t2b[(uint)n*64u + lane];
  float s0 = a0*bflo(ps), s1 = a0*bfhi(ps);
  float vden = 0.f;
  int beg = rowptr[n], end = rowptr[n+1];
  for (int e = beg; e < end; e += 64){
    int ej = e + (int)lane;
    uint  mc = (uint)col[(ej < end) ? ej : (end-1)];  // clamp: broadcast lanes reuse cached row
    float ml = al_s[mc];
    float ma = (ej < end) ? exp2f(leaky(ml + ald)) : 0.f;
    vden += ma;
    int rem = end - e;                        // wave-uniform
    #pragma unroll
    for (int jb = 0; jb < 4; ++jb){
      if (jb*16 < rem){                       // wave-uniform guard
        #pragma unroll
        for (int j = 0; j < 16; ++j){
          int lsrc = jb*16 + j;
          float a = rdlanef(ma, lsrc);        // SGPR broadcast (alpha==0 for invalid)
          uint  c = (uint)__builtin_amdgcn_readlane((int)mc, lsrc);
          uint  p = t2b[c*64u + lane];        // scalar-base + lane offset
          s0 = fmaf(a, bflo(p), s0);
          s1 = fmaf(a, bfhi(p), s1);
        }
      }
    }
  }
  #pragma unroll
  for (int m = 32; m >= 1; m >>= 1) vden += __shfl_xor(vden, m, 64);
  float inv = 1.f/(a0 + vden + 1e-16f);
  float2 bb = ((const float2*)b2)[lane];
  outb[(uint)n*64u + lane] = packbf(s0*inv + bb.x, s1*inv + bb.y);
}

// ---------------- MFMA bf16 GEMM: [M,128]x[128,128], LDS-free, fused epilogue ----------------
template<bool RELU, bool BIAS, bool RES, bool LNRED, bool AL2>
__global__ __launch_bounds__(256) void k_mfma(const uint* __restrict__ Xb, const uint* __restrict__ WTb,
    const float* __restrict__ bias, const uint* __restrict__ resb, uint* __restrict__ outb,
    float* __restrict__ pbuf, const float* __restrict__ avs, const float* __restrict__ avd,
    float* __restrict__ o_als, float* __restrict__ o_ald, int nrows){
  int lane = threadIdx.x & 63;
  int wid  = threadIdx.x >> 6;
  int m0 = blockIdx.x*128 + wid*32;
  int lr = lane & 15, hi4 = lane >> 4;
  f32x4 acc[2][8];
  #pragma unroll
  for (int a = 0; a < 2; ++a)
    #pragma unroll
    for (int c = 0; c < 8; ++c) acc[a][c] = (f32x4){0.f,0.f,0.f,0.f};
  int ra0 = m0 + lr;      if (ra0 > NN-1) ra0 = NN-1;
  int ra1 = m0 + 16 + lr; if (ra1 > NN-1) ra1 = NN-1;
  #pragma unroll
  for (int kk = 0; kk < 4; ++kk){
    int ko = kk*16 + hi4*4;
    bf16x8 a0 = ld8(Xb + (size_t)ra0*64 + ko);
    bf16x8 a1 = ld8(Xb + (size_t)ra1*64 + ko);
    #pragma unroll
    for (int c = 0; c < 8; ++c){
      bf16x8 b = ld8(WTb + (size_t)(c*16 + lr)*64 + ko);
      acc[0][c] = __builtin_amdgcn_mfma_f32_16x16x32_bf16(a0, b, acc[0][c], 0, 0, 0);
      acc[1][c] = __builtin_amdgcn_mfma_f32_16x16x32_bf16(a1, b, acc[1][c], 0, 0, 0);
    }
  }
  if (AL2){
    #pragma unroll
    for (int rg = 0; rg < 2; ++rg){
      #pragma unroll
      for (int r = 0; r < 4; ++r){
        float vs = 0.f, vd = 0.f;
        #pragma unroll
        for (int c = 0; c < 8; ++c){
          float v = acc[rg][c][r];
          vs = fmaf(v, avs[c*16 + lr], vs);
          vd = fmaf(v, avd[c*16 + lr], vd);
        }
        #pragma unroll
        for (int m = 8; m >= 1; m >>= 1){ vs += __shfl_xor(vs, m, 64); vd += __shfl_xor(vd, m, 64); }
        int row = m0 + rg*16 + hi4*4 + r;
        if (lr == 0 && row < nrows){ o_als[row] = vs*LOG2E; o_ald[row] = vd*LOG2E; }
      }
    }
  }
  bool evn = !(lane & 1);
  int cph = lr >> 1;
  float lns = 0.f, lnss = 0.f;
  #pragma unroll
  for (int rg = 0; rg < 2; ++rg){
    #pragma unroll
    for (int c = 0; c < 8; ++c){
      int cp = c*8 + cph;
      #pragma unroll
      for (int r = 0; r < 4; ++r){
        float v0 = acc[rg][c][r];
        float v1 = __shfl_xor(v0, 1, 64);
        int row = m0 + rg*16 + hi4*4 + r;
        if (evn && row < nrows){
          if (BIAS){ float2 bb = ((const float2*)bias)[cp]; v0 += bb.x; v1 += bb.y; }
          if (RES){ uint rr = resb[(size_t)row*64 + cp]; v0 += bflo(rr); v1 += bfhi(rr); }
          if (RELU){ v0 = fmaxf(v0, 0.f); v1 = fmaxf(v1, 0.f); }
          outb[(size_t)row*64 + cp] = packbf(v0, v1);
          if (LNRED){ lns += v0 + v1; lnss += v0*v0 + v1*v1; }
        }
      }
    }
  }
  if (LNRED){
    #pragma unroll
    for (int m = 32; m >= 1; m >>= 1){ lns += __shfl_xor(lns, m, 64); lnss += __shfl_xor(lnss, m, 64); }
    __shared__ float shred[8];
    if (lane == 0){ shred[wid*2] = lns; shred[wid*2+1] = lnss; }
    __syncthreads();
    if (threadIdx.x == 0){
      float S = 0.f, SS = 0.f;
      for (int w = 0; w < 4; ++w){ S += shred[2*w]; SS += shred[2*w+1]; }
      pbuf[blockIdx.x*2] = S; pbuf[blockIdx.x*2+1] = SS;
    }
  }
}

// ---------------- LN stats from per-block partials (LN2 path) ----------------
__global__ __launch_bounds__(256) void k_ln_stats(const float* __restrict__ pbuf, float* __restrict__ stats, int nb){
  float s = 0.f, ss = 0.f;
  for (int i = threadIdx.x; i < nb; i += 256){ s += pbuf[2*i]; ss += pbuf[2*i+1]; }
  #pragma unroll
  for (int m = 32; m >= 1; m >>= 1){ s += __shfl_xor(s, m, 64); ss += __shfl_xor(ss, m, 64); }
  __shared__ float sh[8];
  int wid = threadIdx.x >> 6, lane = threadIdx.x & 63;
  if (lane == 0){ sh[wid*2] = s; sh[wid*2+1] = ss; }
  __syncthreads();
  if (threadIdx.x == 0){
    float S = 0.f, SS = 0.f;
    for (int w = 0; w < 4; ++w){ S += sh[2*w]; SS += sh[2*w+1]; }
    const float inv = 1.f/((float)NN*(float)DD);
    float mu = S*inv;
    float var = SS*inv - mu*mu;
    stats[0] = mu;
    stats[1] = rsqrtf(var + 1e-5f);
  }
}

// ---------------- LN1 apply with inline stats (reads pbuf directly) ----------------
__global__ __launch_bounds__(256) void k_ln_apply_bf(uint* __restrict__ xb, const float* __restrict__ g,
    const float* __restrict__ be, const float* __restrict__ pbuf, int nb){
  __shared__ float sh[8];
  __shared__ float st[2];
  {
    float s = 0.f, ss = 0.f;
    for (int i = threadIdx.x; i < nb; i += 256){ s += pbuf[2*i]; ss += pbuf[2*i+1]; }
    #pragma unroll
    for (int m = 32; m >= 1; m >>= 1){ s += __shfl_xor(s, m, 64); ss += __shfl_xor(ss, m, 64); }
    int wid = threadIdx.x >> 6, lane = threadIdx.x & 63;
    if (lane == 0){ sh[wid*2] = s; sh[wid*2+1] = ss; }
    __syncthreads();
    if (threadIdx.x == 0){
      float S = 0.f, SS = 0.f;
      for (int w = 0; w < 4; ++w){ S += sh[2*w]; SS += sh[2*w+1]; }
      const float inv = 1.f/((float)NN*(float)DD);
      float mu = S*inv;
      float var = SS*inv - mu*mu;
      st[0] = mu;
      st[1] = rsqrtf(var + 1e-5f);
    }
    __syncthreads();
  }
  const int n4 = NN*16;
  float mu = st[0], rs = st[1];
  uint4* x4 = (uint4*)xb;
  const float2* g2 = (const float2*)g;
  const float2* b2 = (const float2*)be;
  for (int i = blockIdx.x*256 + threadIdx.x; i < n4; i += gridDim.x*256){
    int cb = (i & 15)*4;
    uint4 u = x4[i];
    float2 ga = g2[cb],   gb = g2[cb+1], gc = g2[cb+2], gd = g2[cb+3];
    float2 ba = b2[cb],   bb = b2[cb+1], bc = b2[cb+2], bd = b2[cb+3];
    u.x = packbf((bflo(u.x)-mu)*rs*ga.x + ba.x, (bfhi(u.x)-mu)*rs*ga.y + ba.y);
    u.y = packbf((bflo(u.y)-mu)*rs*gb.x + bb.x, (bfhi(u.y)-mu)*rs*gb.y + bb.y);
    u.z = packbf((bflo(u.z)-mu)*rs*gc.x + bc.x, (bfhi(u.z)-mu)*rs*gc.y + bc.y);
    u.w = packbf((bflo(u.w)-mu)*rs*gd.x + bd.x, (bfhi(u.w)-mu)*rs*gd.y + bd.y);
    x4[i] = u;
  }
}

// ---------------- fused LN2-apply + final dot ----------------
__global__ __launch_bounds__(256) void k_fdot_ln(const uint* __restrict__ xb, const float* __restrict__ g,
    const float* __restrict__ be, const float* __restrict__ stats,
    const float* __restrict__ fw, const float* __restrict__ fb, float* __restrict__ val){
  int n = __builtin_amdgcn_readfirstlane(blockIdx.x*4 + (int)(threadIdx.x >> 6));
  if (n >= NN) return;
  int lane = threadIdx.x & 63;
  float mu = stats[0], rs = stats[1];
  uint p = xb[(size_t)n*64 + lane];
  float2 gg = ((const float2*)g)[lane];
  float2 bb = ((const float2*)be)[lane];
  float2 ww = ((const float2*)fw)[lane];
  float v = ((bflo(p)-mu)*rs*gg.x + bb.x)*ww.x + ((bfhi(p)-mu)*rs*gg.y + bb.y)*ww.y;
  #pragma unroll
  for (int m = 32; m >= 1; m >>= 1) v += __shfl_xor(v, m, 64);
  if (lane == 0) val[n] = v + fb[0];
}

// ---------------- segment mean over sorted batch ----------------
__global__ __launch_bounds__(64) void k_pool(const float* __restrict__ val, const int* __restrict__ batch,
                                             float* __restrict__ out){
  int g = blockIdx.x;
  int lane = threadIdx.x;
  int lo = 0, hi = NN;
  while (lo < hi){ int mid = (lo+hi)>>1; if (batch[mid] < g) lo = mid+1; else hi = mid; }
  int start = lo;
  hi = NN;
  while (lo < hi){ int mid = (lo+hi)>>1; if (batch[mid] < g+1) lo = mid+1; else hi = mid; }
  int end = lo;
  float s = 0.f;
  for (int i = start + lane; i < end; i += 64) s += val[i];
  #pragma unroll
  for (int m = 32; m >= 1; m >>= 1) s += __shfl_xor(s, m, 64);
  if (lane == 0) out[g] = s / fmaxf((float)(end - start), 1.f);
}

extern "C" void kernel_launch(void* const* d_in, const int* in_sizes, int n_in,
                              void* d_out, int out_size, void* d_ws, size_t ws_size,
                              hipStream_t stream){
  const float* x   = (const float*)d_in[0];
  const int*   ei  = (const int*)d_in[1];
  const int* batch = (const int*)d_in[2];
  const float* W1  = (const float*)d_in[3];
  const float* as1 = (const float*)d_in[4];
  const float* ad1 = (const float*)d_in[5];
  const float* b1  = (const float*)d_in[6];
  const float* W2  = (const float*)d_in[7];
  const float* as2 = (const float*)d_in[8];
  const float* ad2 = (const float*)d_in[9];
  const float* b2  = (const float*)d_in[10];
  const float* fc1w= (const float*)d_in[11];
  const float* fc1b= (const float*)d_in[12];
  const float* fc2w= (const float*)d_in[13];
  const float* fc2b= (const float*)d_in[14];
  const float* fc3w= (const float*)d_in[15];
  const float* fc3b= (const float*)d_in[16];
  const float* fc4w= (const float*)d_in[17];
  const float* fc4b= (const float*)d_in[18];
  const float* g1  = (const float*)d_in[19];
  const float* be1 = (const float*)d_in[20];
  const float* g2  = (const float*)d_in[21];
  const float* be2 = (const float*)d_in[22];
  const float* fcw = (const float*)d_in[23];
  const float* fcb = (const float*)d_in[24];
  float* out = (float*)d_out;
  (void)in_sizes; (void)n_in; (void)out_size; (void)ws_size;

  char* ws = (char*)d_ws;
  size_t off = 0;
  auto alloc = [&](size_t bytes)->void*{
    void* p = ws + off;
    off += (bytes + 255) & ~(size_t)255;
    return p;
  };
  float* A    = (float*)alloc((size_t)NN*DD*4);   // aliases: hist (CSR), t1b/t2b, fc1/fc3 out (bf16)
  float* B    = (float*)alloc((size_t)NN*DD*4);   // h1 / gat2-out / fc4-out (bf16)
  float* C    = (float*)alloc((size_t)NN*DD*4);   // fc2-out / LN1-out (bf16)
  float* als1 = (float*)alloc((size_t)NN*NH*4);
  float* ald1 = (float*)alloc((size_t)NN*NH*4);
  float* als2 = (float*)alloc((size_t)NN*4);
  float* ald2 = (float*)alloc((size_t)NN*4);
  float* escr = (float*)alloc((size_t)NE*4);      // ebuf during CSR build only
  int*   rowptr = (int*)alloc((size_t)(NN+1)*4);
  int*   col    = (int*)alloc((size_t)(NE+64)*4); // +64 zero padding for gat1's unclamped chunk loads
  int*   bsum   = (int*)alloc((size_t)NBK*4);
  int*   bbase  = (int*)alloc((size_t)NBK*4);
  float* pbuf   = (float*)alloc(1024*2*4);
  float* stats  = (float*)alloc(2*4);
  float* val    = (float*)alloc((size_t)NN*4);
  uint* wt_fc1  = (uint*)alloc((size_t)DD*64*4);
  uint* wt_fc2  = (uint*)alloc((size_t)DD*64*4);
  uint* wt_w2   = (uint*)alloc((size_t)DD*64*4);
  uint* wt_fc3  = (uint*)alloc((size_t)DD*64*4);
  uint* wt_fc4  = (uint*)alloc((size_t)DD*64*4);

  uint*  Ab     = (uint*)A;
  uint*  Bb     = (uint*)B;
  uint*  Cb     = (uint*)C;
  int*   hist   = (int*)A;      // A dead during CSR build (NBLK*NBK ints = 200 KB)
  uint*  ebuf   = (uint*)escr;

  const int* esrc = ei;
  const int* edst = ei + NE;

  hipMemsetAsync(col + NE, 0, 64*4, stream);      // zero padding (reads node 0's cached row)

  // ---- CSR build (atomic-free partition, 512-node buckets) ----
  k_hist <<<NBLK, 512, 0, stream>>>(edst, hist);
  k_bsumscan<<<1, 256, 0, stream>>>(hist, bsum, bbase);
  k_part <<<NBLK, 512, 0, stream>>>(esrc, edst, hist, bbase, ebuf);
  k_fin  <<<NBK, 256, 0, stream>>>(ebuf, bbase, bsum, rowptr, col);

  // ---- all 5 weight converts in one launch ----
  k_wconv5<<<5*DD, 64, 0, stream>>>(fc1w, fc2w, W2, fc3w, fc4w,
                                    wt_fc1, wt_fc2, wt_w2, wt_fc3, wt_fc4);

  const int WB = (NN + 3)/4;     // wave-per-node kernels
  const int GB = (NN + 127)/128; // MFMA GEMM blocks

  // GAT layer 1 (bf16 feature table in Ab), fused softmax+gather
  k_lin1<<<NN, 128, 0, stream>>>(x, W1, as1, ad1, Ab, als1, ald1);
  k_gat1<<<WB, 256, 0, stream>>>(Ab, als1, ald1, rowptr, col, b1, Bb);

  // fc1 (relu) -> Ab ; fc2 (+res h1, relu, LN-reduce) -> Cb
  k_mfma<true,  true, false, false, false><<<GB, 256, 0, stream>>>(Bb, wt_fc1, fc1b, nullptr, Ab, nullptr, nullptr, nullptr, nullptr, nullptr, NN);
  k_mfma<true,  true, true,  true,  false><<<GB, 256, 0, stream>>>(Ab, wt_fc2, fc2b, Bb,      Cb, pbuf,    nullptr, nullptr, nullptr, nullptr, NN);

  // LN1 (graph mode, bf16 in place, stats inline)
  k_ln_apply_bf<<<1024, 256, 0, stream>>>(Cb, g1, be1, pbuf, GB);

  // GAT layer 2: t2b = Cb @ W2 -> Ab, logits fused in epilogue; then fused softmax+gather
  k_mfma<false, false, false, false, true ><<<GB, 256, 0, stream>>>(Cb, wt_w2, nullptr, nullptr, Ab, nullptr, as2, ad2, als2, ald2, NN);
  k_gat2<<<WB, 256, 0, stream>>>(Ab, als2, ald2, rowptr, col, b2, Bb);

  // fc3 (relu) -> Ab ; fc4 (+res LN1-out Cb, LN-reduce) -> Bb
  k_mfma<true,  true, false, false, false><<<GB, 256, 0, stream>>>(Bb, wt_fc3, fc3b, nullptr, Ab, nullptr, nullptr, nullptr, nullptr, nullptr, NN);
  k_mfma<false, true, true,  true,  false><<<GB, 256, 0, stream>>>(Ab, wt_fc4, fc4b, Cb,      Bb, pbuf,    nullptr, nullptr, nullptr, nullptr, NN);

  // LN2 stats, fused LN2-apply + final dot, pool
  k_ln_stats<<<1, 256, 0, stream>>>(pbuf, stats, GB);
  k_fdot_ln<<<WB, 256, 0, stream>>>(Bb, g2, be2, stats, fcw, fcb, val);
  k_pool<<<NG, 64, 0, stream>>>(val, batch, out);
}

// Round 18
// 455.900 us; speedup vs baseline: 1.0530x; 1.0530x over previous
//
#include <hip/hip_runtime.h>
#include <cstdint>

#define NN 100000
#define NE 1600000
#define DI 9
#define DD 128
#define NH 8
#define NG 1000
#define LOG2E 1.44269504f

#define NBK 196             // buckets = dst>>9 (512 nodes each; 196*512 >= 100000)
#define NBLK 256            // partition blocks
#define EPB (NE/NBLK)       // 6250 edges per block (exact)

typedef unsigned int uint;
typedef __attribute__((ext_vector_type(8))) short bf16x8;
typedef __attribute__((ext_vector_type(4))) float f32x4;

__device__ __forceinline__ float leaky(float x){ return fmaxf(x, 0.2f*x); }
__device__ __forceinline__ uint f2bf(float f){            // round-to-nearest-even bf16
  uint u = __float_as_uint(f);
  return (u + 0x7fffu + ((u>>16)&1u)) >> 16;
}
__device__ __forceinline__ float bflo(uint p){ return __uint_as_float(p << 16); }
__device__ __forceinline__ float bfhi(uint p){ return __uint_as_float(p & 0xffff0000u); }
__device__ __forceinline__ uint packbf(float a, float b){ return f2bf(a) | (f2bf(b)<<16); }
__device__ __forceinline__ float rdlanef(float v, int l){
  return __uint_as_float((uint)__builtin_amdgcn_readlane((int)__float_as_uint(v), l));
}

union U16 { uint4 u; bf16x8 v; };
__device__ __forceinline__ bf16x8 ld8(const uint* p){ U16 t; t.u = *(const uint4*)p; return t.v; }

// ================= CSR build: atomic-free bucket partition (512-node buckets) =================
// ebuf packing: src (20 bits) | dst_low9 << 20
__global__ __launch_bounds__(512) void k_hist(const int* __restrict__ dst, int* __restrict__ hist){
  __shared__ int h[NBK];
  for (int i = threadIdx.x; i < NBK; i += 512) h[i] = 0;
  __syncthreads();
  int blk = blockIdx.x;
  int beg = blk*EPB, end = beg + EPB;
  for (int i = beg + threadIdx.x; i < end; i += 512)
    atomicAdd(&h[dst[i] >> 9], 1);
  __syncthreads();
  for (int b = threadIdx.x; b < NBK; b += 512) hist[blk*NBK + b] = h[b];
}

// merged bsum + bscan: one block
__global__ __launch_bounds__(256) void k_bsumscan(int* __restrict__ hist, int* __restrict__ bsum,
                                                  int* __restrict__ bbase){
  __shared__ int sh[256];
  int t = threadIdx.x;
  int run = 0;
  if (t < NBK){
    for (int k = 0; k < NBLK; ++k){
      int v = hist[k*NBK + t];
      hist[k*NBK + t] = run;
      run += v;
    }
    bsum[t] = run;
  }
  sh[t] = (t < NBK) ? run : 0;
  __syncthreads();
  for (int off = 1; off < 256; off <<= 1){
    int v = (t >= off) ? sh[t-off] : 0;
    __syncthreads();
    sh[t] += v;
    __syncthreads();
  }
  if (t < NBK) bbase[t] = sh[t] - run;
}

__global__ __launch_bounds__(512) void k_part(const int* __restrict__ src, const int* __restrict__ dst,
    const int* __restrict__ hist, const int* __restrict__ bbase, uint* __restrict__ ebuf){
  __shared__ int cur[NBK];
  int blk = blockIdx.x;
  for (int b = threadIdx.x; b < NBK; b += 512)
    cur[b] = hist[blk*NBK + b] + bbase[b];
  __syncthreads();
  int beg = blk*EPB, end = beg + EPB;
  for (int i = beg + threadIdx.x; i < end; i += 512){
    int d = dst[i], s = src[i];
    int b = d >> 9;
    int p = atomicAdd(&cur[b], 1);              // LDS atomic; runs of ~32 edges (128B) per cursor
    ebuf[p] = (uint)s | ((uint)(d & 511) << 20);
  }
}

// per 512-node bucket: count-sort by dst_low9; writes rowptr AND col
__global__ __launch_bounds__(256) void k_fin(const uint* __restrict__ ebuf, const int* __restrict__ bbase,
    const int* __restrict__ bsum, int* __restrict__ rowptr, int* __restrict__ col){
  __shared__ int cnt[512];
  __shared__ int sc[256];
  int b = blockIdx.x;
  int t = threadIdx.x;
  int nb0 = b*512;
  int nodes = NN - nb0; if (nodes > 512) nodes = 512;
  cnt[t] = 0; cnt[t+256] = 0;
  __syncthreads();
  int base = bbase[b], n = bsum[b];
  for (int i = t; i < n; i += 256)
    atomicAdd(&cnt[ebuf[base+i] >> 20], 1);
  __syncthreads();
  int a0 = cnt[2*t], a1 = cnt[2*t+1];
  int pairsum = a0 + a1;
  sc[t] = pairsum;
  __syncthreads();
  for (int off = 1; off < 256; off <<= 1){
    int v = (t >= off) ? sc[t-off] : 0;
    __syncthreads();
    sc[t] += v;
    __syncthreads();
  }
  int excl = sc[t] - pairsum;        // exclusive over pairs
  __syncthreads();
  cnt[2*t]   = excl;
  cnt[2*t+1] = excl + a0;
  if (2*t   < nodes) rowptr[nb0 + 2*t]   = base + excl;
  if (2*t+1 < nodes) rowptr[nb0 + 2*t+1] = base + excl + a0;
  __syncthreads();
  for (int i = t; i < n; i += 256){
    uint e = ebuf[base+i];
    int d = (int)(e >> 20);
    int r = atomicAdd(&cnt[d], 1);
    col[base + r] = (int)(e & 0xFFFFFu);
  }
  if (b == 0 && t == 0) rowptr[NN] = NE;
}

// ---------------- 5 weight converts in one launch ----------------
__global__ __launch_bounds__(64) void k_wconv5(const float* __restrict__ w0, const float* __restrict__ w1,
    const float* __restrict__ w2, const float* __restrict__ w3, const float* __restrict__ w4,
    uint* __restrict__ o0, uint* __restrict__ o1, uint* __restrict__ o2,
    uint* __restrict__ o3, uint* __restrict__ o4){
  int which = blockIdx.x >> 7;
  int n = blockIdx.x & 127;
  int t = threadIdx.x;
  const float* W = (which==0)?w0:(which==1)?w1:(which==2)?w2:(which==3)?w3:w4;
  uint* WT = (which==0)?o0:(which==1)?o1:(which==2)?o2:(which==3)?o3:o4;
  float a = W[(2*t)*DD + n];
  float b = W[(2*t+1)*DD + n];
  WT[n*64 + t] = packbf(a, b);
}

// ---------------- GAT1 linear (x@W1) + logits (pre-scaled by log2e); bf16 table ----------------
__global__ __launch_bounds__(128) void k_lin1(const float* __restrict__ x, const float* __restrict__ W1,
    const float* __restrict__ as1, const float* __restrict__ ad1,
    uint* __restrict__ t1b, float* __restrict__ al_s, float* __restrict__ al_d){
  int n = blockIdx.x;
  int c = threadIdx.x;
  const float* xr = x + n*DI;
  float t = 0.f;
  #pragma unroll
  for (int k = 0; k < DI; ++k) t = fmaf(xr[k], W1[k*DD+c], t);
  uint mybf = f2bf(t);
  uint pbf  = (uint)__shfl_xor((int)mybf, 1, 64);
  if (!(c & 1)) t1b[(size_t)n*64 + (c>>1)] = mybf | (pbf<<16);
  float vs = t * as1[c];
  float vd = t * ad1[c];
  #pragma unroll
  for (int m = 8; m >= 1; m >>= 1){ vs += __shfl_xor(vs, m, 16); vd += __shfl_xor(vd, m, 16); }
  if ((c & 15) == 0){
    al_s[n*NH + (c>>4)] = vs*LOG2E;
    al_d[n*NH + (c>>4)] = vd*LOG2E;
  }
}

// ---------------- GAT1 fused: inline softmax + gather, sequential unroll 8 (r12 form, exp2) ----------------
__global__ __launch_bounds__(256) void k_gat1(const uint* __restrict__ t1b,
    const float* __restrict__ al_s, const float* __restrict__ al_d,
    const int* __restrict__ rowptr, const int* __restrict__ col,
    const float* __restrict__ b1, uint* __restrict__ outb){
  int n = blockIdx.x*4 + (threadIdx.x >> 6);
  if (n >= NN) return;
  uint lane = threadIdx.x & 63;
  uint h = lane >> 3;
  float ald = al_d[(uint)n*NH + h];
  float a0  = exp2f(leaky(al_s[(uint)n*NH + h] + ald));   // self-loop
  uint  ps  = t1b[(uint)n*64u + lane];
  float den = a0;
  float s0 = a0*bflo(ps), s1 = a0*bfhi(ps);
  int beg = rowptr[n], end = rowptr[n+1];
  int e = beg;
  for (; e + 8 <= end; e += 8){
    uint c0 = (uint)col[e],   c1 = (uint)col[e+1], c2 = (uint)col[e+2], c3 = (uint)col[e+3];
    uint c4 = (uint)col[e+4], c5 = (uint)col[e+5], c6 = (uint)col[e+6], c7 = (uint)col[e+7];
    float l0 = al_s[c0*8u + h], l1 = al_s[c1*8u + h], l2 = al_s[c2*8u + h], l3 = al_s[c3*8u + h];
    float l4 = al_s[c4*8u + h], l5 = al_s[c5*8u + h], l6 = al_s[c6*8u + h], l7 = al_s[c7*8u + h];
    uint p0 = t1b[c0*64u + lane], p1 = t1b[c1*64u + lane];
    uint p2 = t1b[c2*64u + lane], p3 = t1b[c3*64u + lane];
    uint p4 = t1b[c4*64u + lane], p5 = t1b[c5*64u + lane];
    uint p6 = t1b[c6*64u + lane], p7 = t1b[c7*64u + lane];
    float a0_ = exp2f(leaky(l0 + ald)), a1_ = exp2f(leaky(l1 + ald));
    float a2_ = exp2f(leaky(l2 + ald)), a3_ = exp2f(leaky(l3 + ald));
    float a4_ = exp2f(leaky(l4 + ald)), a5_ = exp2f(leaky(l5 + ald));
    float a6_ = exp2f(leaky(l6 + ald)), a7_ = exp2f(leaky(l7 + ald));
    den += a0_ + a1_ + a2_ + a3_ + a4_ + a5_ + a6_ + a7_;
    s0 = fmaf(a0_, bflo(p0), s0); s1 = fmaf(a0_, bfhi(p0), s1);
    s0 = fmaf(a1_, bflo(p1), s0); s1 = fmaf(a1_, bfhi(p1), s1);
    s0 = fmaf(a2_, bflo(p2), s0); s1 = fmaf(a2_, bfhi(p2), s1);
    s0 = fmaf(a3_, bflo(p3), s0); s1 = fmaf(a3_, bfhi(p3), s1);
    s0 = fmaf(a4_, bflo(p4), s0); s1 = fmaf(a4_, bfhi(p4), s1);
    s0 = fmaf(a5_, bflo(p5), s0); s1 = fmaf(a5_, bfhi(p5), s1);
    s0 = fmaf(a6_, bflo(p6), s0); s1 = fmaf(a6_, bfhi(p6), s1);
    s0 = fmaf(a7_, bflo(p7), s0); s1 = fmaf(a7_, bfhi(p7), s1);
  }
  for (; e < end; ++e){
    uint c = (uint)col[e];
    float a = exp2f(leaky(al_s[c*8u + h] + ald));
    uint p = t1b[c*64u + lane];
    den += a;
    s0 = fmaf(a, bflo(p), s0); s1 = fmaf(a, bfhi(p), s1);
  }
  float inv = 1.f/(den + 1e-16f);
  float2 bb = ((const float2*)b1)[lane];
  outb[(uint)n*64u + lane] = packbf(fmaxf(s0*inv + bb.x, 0.f), fmaxf(s1*inv + bb.y, 0.f));
}

// ---------------- GAT2 fused: 64-edge chunks, lane-parallel alpha + readlane broadcast (clamped) ----------------
__global__ __launch_bounds__(256) void k_gat2(const uint* __restrict__ t2b,
    const float* __restrict__ al_s, const float* __restrict__ al_d,
    const int* __restrict__ rowptr, const int* __restrict__ col,
    const float* __restrict__ b2, uint* __restrict__ outb){
  int n = blockIdx.x*4 + (threadIdx.x >> 6);
  if (n >= NN) return;
  uint lane = threadIdx.x & 63;
  float ald = al_d[n];
  float a0  = exp2f(leaky(al_s[n] + ald));
  uint  ps  = t2b[(uint)n*64u + lane];
  float s0 = a0*bflo(ps), s1 = a0*bfhi(ps);
  float vden = 0.f;
  int beg = rowptr[n], end = rowptr[n+1];
  for (int e = beg; e < end; e += 64){
    int ej = e + (int)lane;
    uint  mc = (uint)col[(ej < end) ? ej : (end-1)];  // clamp: broadcast lanes reuse cached row
    float ml = al_s[mc];
    float ma = (ej < end) ? exp2f(leaky(ml + ald)) : 0.f;
    vden += ma;
    int rem = end - e;                        // wave-uniform
    #pragma unroll
    for (int jb = 0; jb < 4; ++jb){
      if (jb*16 < rem){                       // wave-uniform guard
        #pragma unroll
        for (int j = 0; j < 16; ++j){
          int lsrc = jb*16 + j;
          float a = rdlanef(ma, lsrc);        // SGPR broadcast (alpha==0 for invalid)
          uint  c = (uint)__builtin_amdgcn_readlane((int)mc, lsrc);
          uint  p = t2b[c*64u + lane];        // scalar-base + lane offset
          s0 = fmaf(a, bflo(p), s0);
          s1 = fmaf(a, bfhi(p), s1);
        }
      }
    }
  }
  #pragma unroll
  for (int m = 32; m >= 1; m >>= 1) vden += __shfl_xor(vden, m, 64);
  float inv = 1.f/(a0 + vden + 1e-16f);
  float2 bb = ((const float2*)b2)[lane];
  outb[(uint)n*64u + lane] = packbf(s0*inv + bb.x, s1*inv + bb.y);
}

// ---------------- MFMA bf16 GEMM: [M,128]x[128,128], LDS-free, fused epilogue ----------------
template<bool RELU, bool BIAS, bool RES, bool LNRED, bool AL2>
__global__ __launch_bounds__(256) void k_mfma(const uint* __restrict__ Xb, const uint* __restrict__ WTb,
    const float* __restrict__ bias, const uint* __restrict__ resb, uint* __restrict__ outb,
    float* __restrict__ pbuf, const float* __restrict__ avs, const float* __restrict__ avd,
    float* __restrict__ o_als, float* __restrict__ o_ald, int nrows){
  int lane = threadIdx.x & 63;
  int wid  = threadIdx.x >> 6;
  int m0 = blockIdx.x*128 + wid*32;
  int lr = lane & 15, hi4 = lane >> 4;
  f32x4 acc[2][8];
  #pragma unroll
  for (int a = 0; a < 2; ++a)
    #pragma unroll
    for (int c = 0; c < 8; ++c) acc[a][c] = (f32x4){0.f,0.f,0.f,0.f};
  int ra0 = m0 + lr;      if (ra0 > NN-1) ra0 = NN-1;
  int ra1 = m0 + 16 + lr; if (ra1 > NN-1) ra1 = NN-1;
  #pragma unroll
  for (int kk = 0; kk < 4; ++kk){
    int ko = kk*16 + hi4*4;
    bf16x8 a0 = ld8(Xb + (size_t)ra0*64 + ko);
    bf16x8 a1 = ld8(Xb + (size_t)ra1*64 + ko);
    #pragma unroll
    for (int c = 0; c < 8; ++c){
      bf16x8 b = ld8(WTb + (size_t)(c*16 + lr)*64 + ko);
      acc[0][c] = __builtin_amdgcn_mfma_f32_16x16x32_bf16(a0, b, acc[0][c], 0, 0, 0);
      acc[1][c] = __builtin_amdgcn_mfma_f32_16x16x32_bf16(a1, b, acc[1][c], 0, 0, 0);
    }
  }
  if (AL2){
    #pragma unroll
    for (int rg = 0; rg < 2; ++rg){
      #pragma unroll
      for (int r = 0; r < 4; ++r){
        float vs = 0.f, vd = 0.f;
        #pragma unroll
        for (int c = 0; c < 8; ++c){
          float v = acc[rg][c][r];
          vs = fmaf(v, avs[c*16 + lr], vs);
          vd = fmaf(v, avd[c*16 + lr], vd);
        }
        #pragma unroll
        for (int m = 8; m >= 1; m >>= 1){ vs += __shfl_xor(vs, m, 64); vd += __shfl_xor(vd, m, 64); }
        int row = m0 + rg*16 + hi4*4 + r;
        if (lr == 0 && row < nrows){ o_als[row] = vs*LOG2E; o_ald[row] = vd*LOG2E; }
      }
    }
  }
  bool evn = !(lane & 1);
  int cph = lr >> 1;
  float lns = 0.f, lnss = 0.f;
  #pragma unroll
  for (int rg = 0; rg < 2; ++rg){
    #pragma unroll
    for (int c = 0; c < 8; ++c){
      int cp = c*8 + cph;
      #pragma unroll
      for (int r = 0; r < 4; ++r){
        float v0 = acc[rg][c][r];
        float v1 = __shfl_xor(v0, 1, 64);
        int row = m0 + rg*16 + hi4*4 + r;
        if (evn && row < nrows){
          if (BIAS){ float2 bb = ((const float2*)bias)[cp]; v0 += bb.x; v1 += bb.y; }
          if (RES){ uint rr = resb[(size_t)row*64 + cp]; v0 += bflo(rr); v1 += bfhi(rr); }
          if (RELU){ v0 = fmaxf(v0, 0.f); v1 = fmaxf(v1, 0.f); }
          outb[(size_t)row*64 + cp] = packbf(v0, v1);
          if (LNRED){ lns += v0 + v1; lnss += v0*v0 + v1*v1; }
        }
      }
    }
  }
  if (LNRED){
    #pragma unroll
    for (int m = 32; m >= 1; m >>= 1){ lns += __shfl_xor(lns, m, 64); lnss += __shfl_xor(lnss, m, 64); }
    __shared__ float shred[8];
    if (lane == 0){ shred[wid*2] = lns; shred[wid*2+1] = lnss; }
    __syncthreads();
    if (threadIdx.x == 0){
      float S = 0.f, SS = 0.f;
      for (int w = 0; w < 4; ++w){ S += shred[2*w]; SS += shred[2*w+1]; }
      pbuf[blockIdx.x*2] = S; pbuf[blockIdx.x*2+1] = SS;
    }
  }
}

// ---------------- LN stats from per-block partials (LN2 path) ----------------
__global__ __launch_bounds__(256) void k_ln_stats(const float* __restrict__ pbuf, float* __restrict__ stats, int nb){
  float s = 0.f, ss = 0.f;
  for (int i = threadIdx.x; i < nb; i += 256){ s += pbuf[2*i]; ss += pbuf[2*i+1]; }
  #pragma unroll
  for (int m = 32; m >= 1; m >>= 1){ s += __shfl_xor(s, m, 64); ss += __shfl_xor(ss, m, 64); }
  __shared__ float sh[8];
  int wid = threadIdx.x >> 6, lane = threadIdx.x & 63;
  if (lane == 0){ sh[wid*2] = s; sh[wid*2+1] = ss; }
  __syncthreads();
  if (threadIdx.x == 0){
    float S = 0.f, SS = 0.f;
    for (int w = 0; w < 4; ++w){ S += sh[2*w]; SS += sh[2*w+1]; }
    const float inv = 1.f/((float)NN*(float)DD);
    float mu = S*inv;
    float var = SS*inv - mu*mu;
    stats[0] = mu;
    stats[1] = rsqrtf(var + 1e-5f);
  }
}

// ---------------- LN1 apply with inline stats (reads pbuf directly) ----------------
__global__ __launch_bounds__(256) void k_ln_apply_bf(uint* __restrict__ xb, const float* __restrict__ g,
    const float* __restrict__ be, const float* __restrict__ pbuf, int nb){
  __shared__ float sh[8];
  __shared__ float st[2];
  {
    float s = 0.f, ss = 0.f;
    for (int i = threadIdx.x; i < nb; i += 256){ s += pbuf[2*i]; ss += pbuf[2*i+1]; }
    #pragma unroll
    for (int m = 32; m >= 1; m >>= 1){ s += __shfl_xor(s, m, 64); ss += __shfl_xor(ss, m, 64); }
    int wid = threadIdx.x >> 6, lane = threadIdx.x & 63;
    if (lane == 0){ sh[wid*2] = s; sh[wid*2+1] = ss; }
    __syncthreads();
    if (threadIdx.x == 0){
      float S = 0.f, SS = 0.f;
      for (int w = 0; w < 4; ++w){ S += sh[2*w]; SS += sh[2*w+1]; }
      const float inv = 1.f/((float)NN*(float)DD);
      float mu = S*inv;
      float var = SS*inv - mu*mu;
      st[0] = mu;
      st[1] = rsqrtf(var + 1e-5f);
    }
    __syncthreads();
  }
  const int n4 = NN*16;
  float mu = st[0], rs = st[1];
  uint4* x4 = (uint4*)xb;
  const float2* g2 = (const float2*)g;
  const float2* b2 = (const float2*)be;
  for (int i = blockIdx.x*256 + threadIdx.x; i < n4; i += gridDim.x*256){
    int cb = (i & 15)*4;
    uint4 u = x4[i];
    float2 ga = g2[cb],   gb = g2[cb+1], gc = g2[cb+2], gd = g2[cb+3];
    float2 ba = b2[cb],   bb = b2[cb+1], bc = b2[cb+2], bd = b2[cb+3];
    u.x = packbf((bflo(u.x)-mu)*rs*ga.x + ba.x, (bfhi(u.x)-mu)*rs*ga.y + ba.y);
    u.y = packbf((bflo(u.y)-mu)*rs*gb.x + bb.x, (bfhi(u.y)-mu)*rs*gb.y + bb.y);
    u.z = packbf((bflo(u.z)-mu)*rs*gc.x + bc.x, (bfhi(u.z)-mu)*rs*gc.y + bc.y);
    u.w = packbf((bflo(u.w)-mu)*rs*gd.x + bd.x, (bfhi(u.w)-mu)*rs*gd.y + bd.y);
    x4[i] = u;
  }
}

// ---------------- fused LN2-apply + final dot ----------------
__global__ __launch_bounds__(256) void k_fdot_ln(const uint* __restrict__ xb, const float* __restrict__ g,
    const float* __restrict__ be, const float* __restrict__ stats,
    const float* __restrict__ fw, const float* __restrict__ fb, float* __restrict__ val){
  int n = blockIdx.x*4 + (threadIdx.x >> 6);
  if (n >= NN) return;
  int lane = threadIdx.x & 63;
  float mu = stats[0], rs = stats[1];
  uint p = xb[(size_t)n*64 + lane];
  float2 gg = ((const float2*)g)[lane];
  float2 bb = ((const float2*)be)[lane];
  float2 ww = ((const float2*)fw)[lane];
  float v = ((bflo(p)-mu)*rs*gg.x + bb.x)*ww.x + ((bfhi(p)-mu)*rs*gg.y + bb.y)*ww.y;
  #pragma unroll
  for (int m = 32; m >= 1; m >>= 1) v += __shfl_xor(v, m, 64);
  if (lane == 0) val[n] = v + fb[0];
}

// ---------------- segment mean over sorted batch ----------------
__global__ __launch_bounds__(64) void k_pool(const float* __restrict__ val, const int* __restrict__ batch,
                                             float* __restrict__ out){
  int g = blockIdx.x;
  int lane = threadIdx.x;
  int lo = 0, hi = NN;
  while (lo < hi){ int mid = (lo+hi)>>1; if (batch[mid] < g) lo = mid+1; else hi = mid; }
  int start = lo;
  hi = NN;
  while (lo < hi){ int mid = (lo+hi)>>1; if (batch[mid] < g+1) lo = mid+1; else hi = mid; }
  int end = lo;
  float s = 0.f;
  for (int i = start + lane; i < end; i += 64) s += val[i];
  #pragma unroll
  for (int m = 32; m >= 1; m >>= 1) s += __shfl_xor(s, m, 64);
  if (lane == 0) out[g] = s / fmaxf((float)(end - start), 1.f);
}

extern "C" void kernel_launch(void* const* d_in, const int* in_sizes, int n_in,
                              void* d_out, int out_size, void* d_ws, size_t ws_size,
                              hipStream_t stream){
  const float* x   = (const float*)d_in[0];
  const int*   ei  = (const int*)d_in[1];
  const int* batch = (const int*)d_in[2];
  const float* W1  = (const float*)d_in[3];
  const float* as1 = (const float*)d_in[4];
  const float* ad1 = (const float*)d_in[5];
  const float* b1  = (const float*)d_in[6];
  const float* W2  = (const float*)d_in[7];
  const float* as2 = (const float*)d_in[8];
  const float* ad2 = (const float*)d_in[9];
  const float* b2  = (const float*)d_in[10];
  const float* fc1w= (const float*)d_in[11];
  const float* fc1b= (const float*)d_in[12];
  const float* fc2w= (const float*)d_in[13];
  const float* fc2b= (const float*)d_in[14];
  const float* fc3w= (const float*)d_in[15];
  const float* fc3b= (const float*)d_in[16];
  const float* fc4w= (const float*)d_in[17];
  const float* fc4b= (const float*)d_in[18];
  const float* g1  = (const float*)d_in[19];
  const float* be1 = (const float*)d_in[20];
  const float* g2  = (const float*)d_in[21];
  const float* be2 = (const float*)d_in[22];
  const float* fcw = (const float*)d_in[23];
  const float* fcb = (const float*)d_in[24];
  float* out = (float*)d_out;
  (void)in_sizes; (void)n_in; (void)out_size; (void)ws_size;

  char* ws = (char*)d_ws;
  size_t off = 0;
  auto alloc = [&](size_t bytes)->void*{
    void* p = ws + off;
    off += (bytes + 255) & ~(size_t)255;
    return p;
  };
  float* A    = (float*)alloc((size_t)NN*DD*4);   // aliases: hist (CSR), t1b/t2b, fc1/fc3 out (bf16)
  float* B    = (float*)alloc((size_t)NN*DD*4);   // h1 / gat2-out / fc4-out (bf16)
  float* C    = (float*)alloc((size_t)NN*DD*4);   // fc2-out / LN1-out (bf16)
  float* als1 = (float*)alloc((size_t)NN*NH*4);
  float* ald1 = (float*)alloc((size_t)NN*NH*4);
  float* als2 = (float*)alloc((size_t)NN*4);
  float* ald2 = (float*)alloc((size_t)NN*4);
  float* escr = (float*)alloc((size_t)NE*4);      // ebuf during CSR build only
  int*   rowptr = (int*)alloc((size_t)(NN+1)*4);
  int*   col    = (int*)alloc((size_t)NE*4);
  int*   bsum   = (int*)alloc((size_t)NBK*4);
  int*   bbase  = (int*)alloc((size_t)NBK*4);
  float* pbuf   = (float*)alloc(1024*2*4);
  float* stats  = (float*)alloc(2*4);
  float* val    = (float*)alloc((size_t)NN*4);
  uint* wt_fc1  = (uint*)alloc((size_t)DD*64*4);
  uint* wt_fc2  = (uint*)alloc((size_t)DD*64*4);
  uint* wt_w2   = (uint*)alloc((size_t)DD*64*4);
  uint* wt_fc3  = (uint*)alloc((size_t)DD*64*4);
  uint* wt_fc4  = (uint*)alloc((size_t)DD*64*4);

  uint*  Ab     = (uint*)A;
  uint*  Bb     = (uint*)B;
  uint*  Cb     = (uint*)C;
  int*   hist   = (int*)A;      // A dead during CSR build (NBLK*NBK ints = 200 KB)
  uint*  ebuf   = (uint*)escr;

  const int* esrc = ei;
  const int* edst = ei + NE;

  // ---- CSR build (atomic-free partition, 512-node buckets) ----
  k_hist <<<NBLK, 512, 0, stream>>>(edst, hist);
  k_bsumscan<<<1, 256, 0, stream>>>(hist, bsum, bbase);
  k_part <<<NBLK, 512, 0, stream>>>(esrc, edst, hist, bbase, ebuf);
  k_fin  <<<NBK, 256, 0, stream>>>(ebuf, bbase, bsum, rowptr, col);

  // ---- all 5 weight converts in one launch ----
  k_wconv5<<<5*DD, 64, 0, stream>>>(fc1w, fc2w, W2, fc3w, fc4w,
                                    wt_fc1, wt_fc2, wt_w2, wt_fc3, wt_fc4);

  const int WB = (NN + 3)/4;     // wave-per-node kernels
  const int GB = (NN + 127)/128; // MFMA GEMM blocks

  // GAT layer 1 (bf16 feature table in Ab), fused softmax+gather
  k_lin1<<<NN, 128, 0, stream>>>(x, W1, as1, ad1, Ab, als1, ald1);
  k_gat1<<<WB, 256, 0, stream>>>(Ab, als1, ald1, rowptr, col, b1, Bb);

  // fc1 (relu) -> Ab ; fc2 (+res h1, relu, LN-reduce) -> Cb
  k_mfma<true,  true, false, false, false><<<GB, 256, 0, stream>>>(Bb, wt_fc1, fc1b, nullptr, Ab, nullptr, nullptr, nullptr, nullptr, nullptr, NN);
  k_mfma<true,  true, true,  true,  false><<<GB, 256, 0, stream>>>(Ab, wt_fc2, fc2b, Bb,      Cb, pbuf,    nullptr, nullptr, nullptr, nullptr, NN);

  // LN1 (graph mode, bf16 in place, stats inline)
  k_ln_apply_bf<<<1024, 256, 0, stream>>>(Cb, g1, be1, pbuf, GB);

  // GAT layer 2: t2b = Cb @ W2 -> Ab, logits fused in epilogue; then fused softmax+gather
  k_mfma<false, false, false, false, true ><<<GB, 256, 0, stream>>>(Cb, wt_w2, nullptr, nullptr, Ab, nullptr, as2, ad2, als2, ald2, NN);
  k_gat2<<<WB, 256, 0, stream>>>(Ab, als2, ald2, rowptr, col, b2, Bb);

  // fc3 (relu) -> Ab ; fc4 (+res LN1-out Cb, LN-reduce) -> Bb
  k_mfma<true,  true, false, false, false><<<GB, 256, 0, stream>>>(Bb, wt_fc3, fc3b, nullptr, Ab, nullptr, nullptr, nullptr, nullptr, nullptr, NN);
  k_mfma<false, true, true,  true,  false><<<GB, 256, 0, stream>>>(Ab, wt_fc4, fc4b, Cb,      Bb, pbuf,    nullptr, nullptr, nullptr, nullptr, NN);

  // LN2 stats, fused LN2-apply + final dot, pool
  k_ln_stats<<<1, 256, 0, stream>>>(pbuf, stats, GB);
  k_fdot_ln<<<WB, 256, 0, stream>>>(Bb, g2, be2, stats, fcw, fcb, val);
  k_pool<<<NG, 64, 0, stream>>>(val, batch, out);
}